// Round 8
// baseline (228.223 us; speedup 1.0000x reference)
//
#include <hip/hip_runtime.h>
#include <hip/hip_bf16.h>
#include <cstdint>
#include <cstddef>

typedef __hip_bfloat16 bf16;
typedef float  floatx4 __attribute__((ext_vector_type(4)));
typedef __bf16 bf16x8  __attribute__((ext_vector_type(8)));

typedef __attribute__((address_space(1))) void as1_void;
typedef __attribute__((address_space(3))) void as3_void;

constexpr int Bn = 4, Ln = 2048, Cn = 1024;

__device__ __forceinline__ void store_one(float* p, float v) { *p = v; }
__device__ __forceinline__ void store_one(bf16*  p, float v) { *p = __float2bfloat16(v); }

// ---------------------------------------------------------------------------
// LESSONS LEDGER
// R1: T2 swizzle verified (SQ_LDS_BANK_CONFLICT == 0).
// R2: NO intra-kernel cross-block sync (fence+spin = coherence storm, +90us).
// R3: NO bulk fp32 global atomics (16.8M adds ~ +20us tax).
// R4: top dispatches = harness ws re-poison fills (~40us, 82% HBM) — fixed.
// R5/R6: counted-vmcnt ledgers already give >=2-phase cover (>> HBM lat);
//     triple-buffer moved NOTHING (total flat). g1 has been ~45us all along:
//     MfmaUtil 29%, per-K-tile 2.8us vs 0.26us of MFMA — stall-bound at
//     1 block/CU (whole CU idles at each phase barrier+wait).
// R7: stall-domain decoupling: universal 128x128 core, 64KB LDS dbuf,
//     __launch_bounds__(512,4) -> 2 blocks/CU; one block's barrier stall
//     overlaps the other's MFMA (m114/m97 evidence). Finer tiles also fill
//     g2 (160->608 blocks) and balance g4 (heavy-K first + backfill).
//     (R7 submit had a 10-arg call typo in g3 — fixed, theory unchanged.)
// ---------------------------------------------------------------------------
#define BAR()    asm volatile("s_barrier" ::: "memory")
#define VMCNT0() asm volatile("s_waitcnt vmcnt(0)" ::: "memory")
#define SCHEDB() __builtin_amdgcn_sched_barrier(0)
#define STAGE(gp, off) \
    __builtin_amdgcn_global_load_lds((const as1_void*)(gp), (as3_void*)(smem + (off)), 16, 0, 0)

// ---------------------------------------------------------------------------
// Universal core: 128(M) x 128(N), BK=64, 8 waves (2M x 4N32), dbuf 64KB.
// R5-proven layout/swizzle. Ledger: all 4 units of tile t+1 issued at phase A
// (buf^1 free: its readers finished at end-D of t-1); single end-D vmcnt(0)
// with 4-phase cover. Two blocks/CU make residual stalls overlap.
// ---------------------------------------------------------------------------
template <typename OutT>
__device__ __forceinline__ void gemm128(
    char* __restrict__ smem,
    const bf16* __restrict__ A, const bf16* __restrict__ B, OutT* __restrict__ C,
    int m0, int n0, int kend, int lda, int ldb, int ldc, float cscale)
{
    const int tid  = threadIdx.x;
    const int lane = tid & 63;
    const int quad = lane >> 4;
    const int lr   = lane & 15;
    const int wave = tid >> 6;
    const int wm   = (wave >> 2) * 64;    // 2 waves along M
    const int wn   = (wave & 3) * 32;     // 4 waves along N

    floatx4 acc[4][2];
#pragma unroll
    for (int i = 0; i < 4; ++i)
#pragma unroll
        for (int j = 0; j < 2; ++j) { floatx4 z = {0.f, 0.f, 0.f, 0.f}; acc[i][j] = z; }

    // staging: pre-swizzled global source, linear LDS dest (T2 + m104 rule)
    const int srow = tid >> 3;                    // 0..63 within a unit
    const int sx   = (tid & 7) ^ (srow & 7);      // inverse-swizzled k-slot
    const bf16* gA = A + (size_t)(m0 + srow) * lda + sx * 8;
    const bf16* gB = B + (size_t)(n0 + srow) * ldb + sx * 8;
    const int wuni = __builtin_amdgcn_readfirstlane((tid & 0x1C0) * 16);

    const int aoff = (wm + lr) * 64;
    const int boff = (wn + lr) * 64;
    const int s0   = (quad ^ (lr & 7)) * 8;       // kk=0 slot; kk=1 is s0^32

    const int NT  = kend >> 6;
    const int BUF = 32768;                        // 16KB A + 16KB B, x2

#define STG4(KN, bo) do { \
        STAGE(gA + (KN),            (bo) + 0 * 8192 + wuni); \
        STAGE(gA + (KN) + 64 * lda, (bo) + 1 * 8192 + wuni); \
        STAGE(gB + (KN),            (bo) + 16384 + 0 * 8192 + wuni); \
        STAGE(gB + (KN) + 64 * ldb, (bo) + 16384 + 1 * 8192 + wuni); } while (0)

    STG4(0, 0);
    VMCNT0();
    BAR();

#define LDA2(PH, SK) do { _Pragma("unroll") for (int ii = 0; ii < 2; ++ii) \
        a[ii] = *(const bf16x8*)(As + aoff + ((PH) * 2 + ii) * 1024 + (SK)); } while (0)
#define LDB2(SK) do { _Pragma("unroll") for (int nn = 0; nn < 2; ++nn) \
        b[nn] = *(const bf16x8*)(Bs + boff + nn * 1024 + (SK)); } while (0)
#define MFMA4(PH) do { _Pragma("unroll") for (int ii = 0; ii < 2; ++ii) { \
        _Pragma("unroll") for (int nn = 0; nn < 2; ++nn) \
            acc[(PH) * 2 + ii][nn] = __builtin_amdgcn_mfma_f32_16x16x32_bf16( \
                a[ii], b[nn], acc[(PH) * 2 + ii][nn], 0, 0, 0); } } while (0)

    for (int t = 0; t < NT; ++t) {
        const bf16* As = (const bf16*)(smem + (t & 1) * BUF);
        const bf16* Bs = (const bf16*)(smem + (t & 1) * BUF + 16384);
        const int  wl  = ((t + 1) & 1) * BUF;
        const int  kn  = (t + 1) << 6;
        const bool more = (t + 1 < NT);
        bf16x8 a[2], b[2];

        // phase A: mi 0-1, kk0  (+ issue ALL of tile t+1 -> 4-phase cover)
        LDB2(s0);
        LDA2(0, s0);
        if (more) STG4(kn, wl);
        BAR(); SCHEDB();
        __builtin_amdgcn_s_setprio(1);
        MFMA4(0);
        __builtin_amdgcn_s_setprio(0);
        SCHEDB();
        BAR();

        // phase B: mi 2-3, kk0
        LDA2(1, s0);
        BAR(); SCHEDB();
        __builtin_amdgcn_s_setprio(1);
        MFMA4(1);
        __builtin_amdgcn_s_setprio(0);
        SCHEDB();
        BAR();

        // phase C: mi 0-1, kk1
        LDB2(s0 ^ 32);
        LDA2(0, s0 ^ 32);
        BAR(); SCHEDB();
        __builtin_amdgcn_s_setprio(1);
        MFMA4(0);
        __builtin_amdgcn_s_setprio(0);
        SCHEDB();
        BAR();

        // phase D: mi 2-3, kk1
        LDA2(1, s0 ^ 32);
        BAR(); SCHEDB();
        __builtin_amdgcn_s_setprio(1);
        MFMA4(1);
        __builtin_amdgcn_s_setprio(0);
        SCHEDB();
        if (more) VMCNT0();                  // tile t+1 resident (issued @A)
        BAR();
    }
#undef LDA2
#undef LDB2
#undef MFMA4
#undef STG4

    // epilogue: C/D layout col=lane&15, row=quad*4+r (m89-verified)
#pragma unroll
    for (int mi = 0; mi < 4; ++mi) {
        const int row = m0 + wm + mi * 16 + quad * 4;
#pragma unroll
        for (int n = 0; n < 2; ++n) {
            const int col = n0 + wn + n * 16 + lr;
            OutT* cp = C + (size_t)row * ldc + col;
#pragma unroll
            for (int r = 0; r < 4; ++r)
                store_one(cp + (size_t)r * ldc, acc[mi][n][r] * cscale);
        }
    }
}

// ---------------------------------------------------------------------------
// g1: QK = Xb . Wqkb^T (8192x2048, K=1024) -> 64mt x 16nt = 1024 tiles,
// single-tile blocks, 2/CU. XCD x = i&7 owns mt in [8x,8x+8) (A 2MB L2-local).
// ---------------------------------------------------------------------------
__global__ __launch_bounds__(512, 4)
void g1_qk(const bf16* __restrict__ Xb, const bf16* __restrict__ Wqkb,
           bf16* __restrict__ QK)
{
    __shared__ __align__(16) char smem[65536];
    const int i = blockIdx.x;                    // 1024
    const int x = i & 7;
    const int r = i >> 3;                        // 0..127
    const int mt = x * 8 + (r & 7);              // 0..63
    const int nt = r >> 3;                       // 0..15
    gemm128<bf16>(smem, Xb, Wqkb, QK, mt * 128, nt * 128, 1024, 1024, 1024, 2048, 1.0f);
}

// ---------------------------------------------------------------------------
// g2: blocks [0,544)  -> S = (Q.K^T)/32: per batch 136 triangular 128-tiles.
//       xcd = i&7 = 2b+p pins batch to an XCD pair (QK panels L2-local).
//     blocks [544,608) -> W2 = Wo.Wv (1024^2): 8x8 tiles.
// 608 uniform blocks at 2/CU (was 160 blocks on 256 CUs = 37% idle).
// ---------------------------------------------------------------------------
__global__ __launch_bounds__(512, 4)
void g2_s_w2(const bf16* __restrict__ QK, const bf16* __restrict__ Wob,
             const bf16* __restrict__ WvT, bf16* __restrict__ S,
             bf16* __restrict__ W2)
{
    __shared__ __align__(16) char smem[65536];
    const int i = blockIdx.x;                    // 608
    if (i < 544) {
        const int b = (i & 7) >> 1;
        const int p = i & 1;
        const int t = (i >> 3) * 2 + p;          // 0..135
        int ti = (int)((sqrtf(8.f * t + 1.f) - 1.f) * 0.5f);
        while ((ti + 1) * (ti + 2) / 2 <= t) ++ti;
        while (ti * (ti + 1) / 2 > t) --ti;
        const int tj = t - ti * (ti + 1) / 2;    // 0..ti, ti<16
        const bf16* Aq = QK + (size_t)b * Ln * 2048;
        const bf16* Bk = Aq + 1024;
        bf16* Sb = S + (size_t)b * Ln * Ln;
        gemm128<bf16>(smem, Aq, Bk, Sb, ti * 128, tj * 128, 1024, 2048, 2048, Ln, 0.03125f);
    } else {
        const int j = i - 544;                   // 0..63
        gemm128<bf16>(smem, Wob, WvT, W2, (j >> 3) * 128, (j & 7) * 128, 1024, 1024, 1024, 1024, 1.0f);
    }
}

// ---------------------------------------------------------------------------
// softmax: 16 rows per block, strided row = i + 512*j (uniform causal mix).
// ---------------------------------------------------------------------------
__device__ __forceinline__ float waveMax(float x) {
#pragma unroll
    for (int o = 32; o > 0; o >>= 1) x = fmaxf(x, __shfl_xor(x, o, 64));
    return x;
}
__device__ __forceinline__ float waveSum(float x) {
#pragma unroll
    for (int o = 32; o > 0; o >>= 1) x += __shfl_xor(x, o, 64);
    return x;
}

__device__ void softmax_rows16(bf16* __restrict__ S, int i)
{
    const int wave = threadIdx.x >> 6, lane = threadIdx.x & 63;
    for (int it2 = 0; it2 < 2; ++it2) {
        const int row = i + 512 * (wave * 2 + it2);   // 0..8191 = b*L + q
        const int q = row & (Ln - 1);
        bf16* Srow = S + (size_t)row * Ln;
        const int kmax = ((q >> 7) + 1) << 7;
        const int nv = (kmax + 511) >> 9;             // 1..4 chunks of 512 cols
        float x[4][8];
        float m = -1e30f;
        for (int it = 0; it < nv; ++it) {
            int c0 = it * 512 + lane * 8;
            bf16x8 v = *(const bf16x8*)(Srow + c0);
#pragma unroll
            for (int e = 0; e < 8; ++e) {
                float f = (float)v[e];
                f = (c0 + e <= q) ? f : -1e30f;
                x[it][e] = f;
                m = fmaxf(m, f);
            }
        }
        m = waveMax(m);
        float s = 0.f;
        for (int it = 0; it < nv; ++it)
#pragma unroll
            for (int e = 0; e < 8; ++e) {
                float ex = (x[it][e] > -1e29f) ? __expf(x[it][e] - m) : 0.f;
                x[it][e] = ex;
                s += ex;
            }
        s = waveSum(s);
        const float inv = 1.f / s;
        for (int it = 0; it < nv; ++it) {
            bf16x8 o;
#pragma unroll
            for (int e = 0; e < 8; ++e) o[e] = (__bf16)(x[it][e] * inv);
            *(bf16x8*)(Srow + it * 512 + lane * 8) = o;
        }
    }
}

// ---------------------------------------------------------------------------
// g3: 512 blocks. Each: one VWT = W2.Xb^T tile (8mh x 64nt, M128 N128) +
// 16 strided softmax rows. XCD x owns nt in [8x,8x+8) (Xb panel L2-local).
// ---------------------------------------------------------------------------
__global__ __launch_bounds__(512, 4)
void g3_vwt_sm(const bf16* __restrict__ W2, const bf16* __restrict__ Xb,
               bf16* __restrict__ VWT, bf16* __restrict__ S)
{
    __shared__ __align__(16) char smem[65536];
    const int i = blockIdx.x;                    // 512
    const int x = i & 7;
    const int r = i >> 3;                        // 0..63
    const int nt = x * 8 + (r & 7);              // 0..63
    const int mh = r >> 3;                       // 0..7
    gemm128<bf16>(smem, W2, Xb, VWT, mh * 128, nt * 128, 1024, 1024, 1024, 8192, 1.0f);
    softmax_rows16(S, i);
}

// ---------------------------------------------------------------------------
// g4: out = P . VW (fp32). 512 single tiles (4b x 16mh x 8nt), causal
// K=(mh+1)*128, HEAVY-FIRST (mh=15 blocks launch first; light tiles backfill
// the 2/CU slots dynamically). xcd = i&7 = 2b+p pins batch to XCD pair.
// ---------------------------------------------------------------------------
__global__ __launch_bounds__(512, 4)
void g4_out(const bf16* __restrict__ P, const bf16* __restrict__ VWT,
            float* __restrict__ out)
{
    __shared__ __align__(16) char smem[65536];
    const int i = blockIdx.x;                    // 512
    const int b = (i & 7) >> 1, p = i & 1;
    const int nt = p * 4 + ((i >> 3) & 3);       // 0..7
    const int mh = 15 - (i >> 5);                // 15..0, heavy first

    const bf16* Pp = P + (size_t)b * Ln * Ln;
    const bf16* Bv = VWT + (size_t)b * Ln;
    float* Co = out + (size_t)b * Ln * Cn;
    gemm128<float>(smem, Pp, Bv, Co, mh * 128, nt * 128, (mh + 1) * 128, Ln, 8192, Cn, 1.0f);
}

// ---------------------------------------------------------------------------
// cast_all: blocks [0,11264)      element-wise fp32->bf16 (X, Wqk rows, Wout)
//           blocks [11264,12288)  transpose-cast Wv (1024x1024) -> WvT
// ---------------------------------------------------------------------------
__global__ __launch_bounds__(256)
void cast_all(const float* __restrict__ X, const float* __restrict__ Wqkv,
              const float* __restrict__ Wo,
              bf16* __restrict__ Xb, bf16* __restrict__ Wqkb,
              bf16* __restrict__ Wob, bf16* __restrict__ WvT)
{
    int blk = blockIdx.x;
    if (blk < 11264) {
        int i = blk * 256 + threadIdx.x;
        const float* src; bf16* dst; int off;
        if (i < 2097152)                 { src = X;    dst = Xb;   off = i; }
        else if (i < 2097152 + 524288)   { src = Wqkv; dst = Wqkb; off = i - 2097152; }
        else                             { src = Wo;   dst = Wob;  off = i - 2621440; }
        float4 f = ((const float4*)src)[off];
        bf16 o0 = __float2bfloat16(f.x), o1 = __float2bfloat16(f.y);
        bf16 o2 = __float2bfloat16(f.z), o3 = __float2bfloat16(f.w);
        ushort4 u;
        u.x = *(unsigned short*)&o0; u.y = *(unsigned short*)&o1;
        u.z = *(unsigned short*)&o2; u.w = *(unsigned short*)&o3;
        *(ushort4*)(dst + (size_t)off * 4) = u;
    } else {
        __shared__ float t[32][33];
        int tt = blk - 11264;
        int c0 = (tt & 31) * 32;
        int r0 = (tt >> 5) * 32;
        const float* Wv = Wqkv + 2048 * 1024;
        int xcol = threadIdx.x & 31, y0 = threadIdx.x >> 5;
#pragma unroll
        for (int p = 0; p < 4; ++p) {
            int y = y0 + 8 * p;
            t[y][xcol] = Wv[(size_t)(r0 + y) * 1024 + c0 + xcol];
        }
        __syncthreads();
#pragma unroll
        for (int p = 0; p < 4; ++p) {
            int mloc = y0 + 8 * p;
            WvT[(size_t)(c0 + mloc) * 1024 + r0 + xcol] = __float2bfloat16(t[xcol][mloc]);
        }
    }
}

// ---------------------------------------------------------------------------
extern "C" void kernel_launch(void* const* d_in, const int* in_sizes, int n_in,
                              void* d_out, int out_size, void* d_ws, size_t ws_size,
                              hipStream_t stream)
{
    const float* X    = (const float*)d_in[0];   // (B,L,C)
    const float* Wqkv = (const float*)d_in[1];   // (3C,C)
    const float* Wout = (const float*)d_in[2];   // (C,C)
    float* out = (float*)d_out;                  // (B,L,C) fp32

    char* ws = (char*)d_ws;
    const size_t MiB = 1024ull * 1024ull;
    bf16* Xb   = (bf16*)(ws + 0);                // 16 MiB
    bf16* QK   = (bf16*)(ws + 16 * MiB);         // 32 MiB (q cols 0..1023, k cols 1024..2047)
    bf16* VWT  = (bf16*)(ws + 48 * MiB);         // 16 MiB (1024 x 8192, ld 8192)
    bf16* Sbuf = (bf16*)(ws + 64 * MiB);         // 32 MiB (P in place)
    bf16* Wqkb = (bf16*)(ws + 96 * MiB);         // 4 MiB
    bf16* WvT  = (bf16*)(ws + 100 * MiB);        // 2 MiB
    bf16* Wob  = (bf16*)(ws + 102 * MiB);        // 2 MiB
    bf16* W2   = (bf16*)(ws + 104 * MiB);        // 2 MiB  (total 106 MiB)

    cast_all<<<dim3(12288), 256, 0, stream>>>(X, Wqkv, Wout, Xb, Wqkb, Wob, WvT);

    g1_qk<<<dim3(1024), 512, 0, stream>>>(Xb, Wqkb, QK);

    g2_s_w2<<<dim3(608), 512, 0, stream>>>(QK, Wob, WvT, Sbuf, W2);

    g3_vwt_sm<<<dim3(512), 512, 0, stream>>>(W2, Xb, VWT, Sbuf);

    g4_out<<<dim3(512), 512, 0, stream>>>(Sbuf, VWT, out);
}